// Round 5
// baseline (346.130 us; speedup 1.0000x reference)
//
#include <hip/hip_runtime.h>
#include <math.h>

#define B_ 2
#define L_ 2048
#define C_ 1024
#define H_ 16
#define M_ (B_*L_)   // 4096 rows

typedef short s16x8 __attribute__((ext_vector_type(8)));
typedef float f32x4 __attribute__((ext_vector_type(4)));

__device__ __forceinline__ unsigned short f2bf(float f) {
    unsigned int u = __float_as_uint(f);
    u += 0x7fffu + ((u >> 16) & 1u);      // RNE
    return (unsigned short)(u >> 16);
}

__device__ __forceinline__ float fexp2(float x) {
#if __has_builtin(__builtin_amdgcn_exp2f)
    return __builtin_amdgcn_exp2f(x);     // raw v_exp_f32 (base-2)
#else
    return exp2f(x);
#endif
}

__device__ __forceinline__ float frcp(float x) {
#if __has_builtin(__builtin_amdgcn_rcpf)
    return __builtin_amdgcn_rcpf(x);      // v_rcp_f32
#else
    return 1.0f / x;
#endif
}

__device__ __forceinline__ void gl_lds16(const void* g, void* l) {
    __builtin_amdgcn_global_load_lds(
        (const __attribute__((address_space(1))) void*)g,
        (__attribute__((address_space(3))) void*)l, 16, 0, 0);
}

#define VMCNT8() asm volatile("s_waitcnt vmcnt(8)" ::: "memory")
#define VMCNT6() asm volatile("s_waitcnt vmcnt(6)" ::: "memory")
#define VMCNT0() asm volatile("s_waitcnt vmcnt(0)" ::: "memory")
#define LGKM0()  asm volatile("s_waitcnt lgkmcnt(0)" ::: "memory")
#define SCHED0() __builtin_amdgcn_sched_barrier(0)

// ---------------- LayerNorm row body (shared by prep + ln2) ----------------
__device__ __forceinline__ void ln_row(const float* __restrict__ x,
                                       const float* __restrict__ w,
                                       const float* __restrict__ b,
                                       unsigned short* __restrict__ out,
                                       int row, int t,
                                       float* red0, float* red1, float* mv) {
    float4 v = ((const float4*)(x + (size_t)row * C_))[t];
    float s  = v.x + v.y + v.z + v.w;
    float s2 = v.x*v.x + v.y*v.y + v.z*v.z + v.w*v.w;
    #pragma unroll
    for (int off = 32; off > 0; off >>= 1) {
        s  += __shfl_down(s, off);
        s2 += __shfl_down(s2, off);
    }
    int wave = t >> 6, lane = t & 63;
    if (lane == 0) { red0[wave] = s; red1[wave] = s2; }
    __syncthreads();
    if (t == 0) {
        float a = red0[0] + red0[1] + red0[2] + red0[3];
        float c = red1[0] + red1[1] + red1[2] + red1[3];
        float mean = a * (1.0f / C_);
        mv[0] = mean;
        mv[1] = rsqrtf(c * (1.0f / C_) - mean * mean + 1e-5f);
    }
    __syncthreads();
    float mean = mv[0], rstd = mv[1];
    float4 wv = ((const float4*)w)[t];
    float4 bv = ((const float4*)b)[t];
    ushort4 o;
    o.x = f2bf((v.x - mean) * rstd * wv.x + bv.x);
    o.y = f2bf((v.y - mean) * rstd * wv.y + bv.y);
    o.z = f2bf((v.z - mean) * rstd * wv.z + bv.z);
    o.w = f2bf((v.w - mean) * rstd * wv.w + bv.w);
    *(ushort4*)&out[(size_t)row * C_ + t * 4] = o;
}

__global__ __launch_bounds__(256) void ln_bf16(const float* __restrict__ x,
                                               const float* __restrict__ w,
                                               const float* __restrict__ b,
                                               unsigned short* __restrict__ out) {
    __shared__ float red0[4], red1[4], mv[2];
    ln_row(x, w, b, out, blockIdx.x, threadIdx.x, red0, red1, mv);
}

// ---------------- prep: 4-way weight transpose+cast  +  LN1 (independent inputs) ----------------
__global__ __launch_bounds__(256) void prep_kernel(
    const float* __restrict__ W0, unsigned short* __restrict__ T0,
    const float* __restrict__ W1, unsigned short* __restrict__ T1,
    const float* __restrict__ W2, unsigned short* __restrict__ T2,
    const float* __restrict__ W3, unsigned short* __restrict__ T3,
    const float* __restrict__ x, const float* __restrict__ lnw,
    const float* __restrict__ lnb, unsigned short* __restrict__ h) {
    __shared__ unsigned short Ts[32][33];
    __shared__ float red0[4], red1[4], mv[2];
    int id = blockIdx.x;
    int t = threadIdx.x;
    if (id >= 12288) {                       // LN1 rows
        ln_row(x, lnw, lnb, h, id - 12288, t, red0, red1, mv);
        return;
    }
    const float* W; unsigned short* WT; int R, C, bx, by;
    if (id < 3072)      { W = W0; WT = T0; R = 1024; C = 3072; bx = id % 96;  by = id / 96; }
    else if (id < 4096) { W = W1; WT = T1; R = 1024; C = 1024; id -= 3072; bx = id & 31;  by = id >> 5; }
    else if (id < 8192) { W = W2; WT = T2; R = 1024; C = 4096; id -= 4096; bx = id & 127; by = id >> 7; }
    else                { W = W3; WT = T3; R = 4096; C = 1024; id -= 8192; bx = id & 31;  by = id >> 5; }
    int tx = t & 31, ty = t >> 5;
    int c0 = bx * 32, r0 = by * 32;
    #pragma unroll
    for (int k = 0; k < 4; ++k)
        Ts[ty + 8*k][tx] = f2bf(W[(size_t)(r0 + ty + 8*k) * C + c0 + tx]);
    __syncthreads();
    #pragma unroll
    for (int k = 0; k < 4; ++k)
        WT[(size_t)(c0 + ty + 8*k) * R + r0 + tx] = Ts[tx][ty + 8*k];
}

// ---------------- bf16 MFMA GEMM, BK=64 (legacy 2-barrier 128-tile) ----------------
__device__ __forceinline__ float gelu_f(float x) {
    // 0.5x(1+tanh(u)) = x / (1 + exp(-2u)); overflow-safe both directions
    float u2 = 1.5957691216057308f * (x + 0.044715f * x * x * x);
    return x * frcp(1.0f + __expf(-u2));
}

// TN = 128 (waves 2x2, 64x64 each) or 64 (waves 2x2, 64x32 each). BK=64.
template<int ACT, int OBF, int TN, int SC, int KS, int VT, int XS>
__global__ __launch_bounds__(256) void bgemm(const unsigned short* __restrict__ A,
                                             const unsigned short* __restrict__ BT,
                                             const float* __restrict__ bias,
                                             const float* __restrict__ res,
                                             void* __restrict__ Cout,
                                             unsigned short* __restrict__ VtP,
                                             int M, int N, int K) {
    __shared__ __align__(16) unsigned short As[128 * 64];   // 16KB
    __shared__ __align__(16) unsigned short Bs[TN * 64];    // 16/8KB
    const int t = threadIdx.x, w = t >> 6, quad = (t & 63) >> 4, ln15 = t & 15;
    constexpr int FJ = TN / 32;
    const int woff_m = (w >> 1) * 64, woff_n = (w & 1) * (TN / 2);
    int bxi = blockIdx.x, byi = blockIdx.y;
    if (XS) {
        int id = bxi + (int)gridDim.x * byi;
        int nt = (int)gridDim.x, xcd = id & 7, loc = id >> 3;
        int per = (nt + 7) >> 3;
        bxi = xcd * per + (loc % per);
        byi = loc / per;
        if (bxi >= nt) { bxi = id % nt; byi = id / nt; }
    }
    const int m0g = byi * 128, n0g = bxi * TN;
    f32x4 acc[4][FJ];
    #pragma unroll
    for (int fi = 0; fi < 4; ++fi)
        #pragma unroll
        for (int fj = 0; fj < FJ; ++fj)
            #pragma unroll
            for (int i = 0; i < 4; ++i) acc[fi][fj][i] = 0.0f;

    const int kbeg = (KS > 1) ? (int)blockIdx.z * (K / KS) : 0;
    const int kiters = ((KS > 1) ? K / KS : K) >> 6;

    const unsigned short* ap[4];
    #pragma unroll
    for (int j = 0; j < 4; ++j) {
        int c = j * 256 + t, row = c >> 3, u = (c & 7) ^ (row & 7);
        ap[j] = A + (size_t)(m0g + row) * K + kbeg + u * 8;
    }
    const unsigned short* bp[FJ];
    #pragma unroll
    for (int j = 0; j < FJ; ++j) {
        int c = j * 256 + t, row = c >> 3, u = (c & 7) ^ (row & 7);
        bp[j] = BT + (size_t)(n0g + row) * K + kbeg + u * 8;
    }

    for (int kk = 0; kk < kiters; ++kk) {
        __syncthreads();
        #pragma unroll
        for (int j = 0; j < 4; ++j) {
            gl_lds16(ap[j], As + (j * 256 + w * 64) * 8);
            ap[j] += 64;
        }
        #pragma unroll
        for (int j = 0; j < FJ; ++j) {
            gl_lds16(bp[j], Bs + (j * 256 + w * 64) * 8);
            bp[j] += 64;
        }
        __syncthreads();
        #pragma unroll
        for (int s = 0; s < 2; ++s) {
            s16x8 af[4], bfr[FJ];
            #pragma unroll
            for (int f = 0; f < 4; ++f) {
                int row = woff_m + f * 16 + ln15;
                af[f] = *(const s16x8*)&As[(row * 8 + ((s * 4 + quad) ^ (row & 7))) * 8];
            }
            #pragma unroll
            for (int f = 0; f < FJ; ++f) {
                int row = woff_n + f * 16 + ln15;
                bfr[f] = *(const s16x8*)&Bs[(row * 8 + ((s * 4 + quad) ^ (row & 7))) * 8];
            }
            #pragma unroll
            for (int fi = 0; fi < 4; ++fi)
                #pragma unroll
                for (int fj = 0; fj < FJ; ++fj)
                    acc[fi][fj] = __builtin_amdgcn_mfma_f32_16x16x32_bf16(af[fi], bfr[fj], acc[fi][fj], 0, 0, 0);
        }
    }

    const int colb = n0g + woff_n + ln15;
    if (KS > 1) {
        float* P = (float*)Cout + (size_t)blockIdx.z * M * N;
        #pragma unroll
        for (int fj = 0; fj < FJ; ++fj) {
            const int col = colb + fj * 16;
            #pragma unroll
            for (int fi = 0; fi < 4; ++fi) {
                const int row0 = m0g + woff_m + fi * 16 + quad * 4;
                #pragma unroll
                for (int i = 0; i < 4; ++i)
                    P[(size_t)(row0 + i) * N + col] = acc[fi][fj][i];
            }
        }
        return;
    }
    #pragma unroll
    for (int fj = 0; fj < FJ; ++fj) {
        const int col = colb + fj * 16;
        const float bv = bias[col];
        const float sc = (SC && col < C_) ? 0.18033688011112042f : 1.0f;
        if (VT && col >= 2 * C_) {
            const int vcol = col - 2 * C_;
            #pragma unroll
            for (int fi = 0; fi < 4; ++fi) {
                const int row0 = m0g + woff_m + fi * 16 + quad * 4;
                const int bb = row0 >> 11, l = row0 & (L_ - 1);
                ushort4 pk;
                pk.x = f2bf(acc[fi][fj][0] + bv);
                pk.y = f2bf(acc[fi][fj][1] + bv);
                pk.z = f2bf(acc[fi][fj][2] + bv);
                pk.w = f2bf(acc[fi][fj][3] + bv);
                *(ushort4*)&VtP[(size_t)(bb * 1024 + vcol) * L_ + l] = pk;
            }
        } else {
            #pragma unroll
            for (int fi = 0; fi < 4; ++fi) {
                const int row0 = m0g + woff_m + fi * 16 + quad * 4;
                #pragma unroll
                for (int i = 0; i < 4; ++i) {
                    float v = acc[fi][fj][i] + bv;
                    if (ACT) v = gelu_f(v);
                    if (SC) v *= sc;
                    size_t off = (size_t)(row0 + i) * N + col;
                    if (res != nullptr) v += res[off];
                    if (OBF) ((unsigned short*)Cout)[off] = f2bf(v);
                    else     ((float*)Cout)[off] = v;
                }
            }
        }
    }
}

// ---------------- bgemm2: deep-pipelined BMx256 tile, BK=64, 512 thr, dbuf LDS ----------------
// One barrier per K-tile; next-next tile prefetch issued right after the barrier;
// counted vmcnt (never 0 in steady state); setprio around 2nd MFMA cluster.
// BM=256: LDS 128KB, waves 2x4 of 128x64. BM=128: LDS 96KB, waves 2x4 of 64x64.
// OBF epilogue goes through LDS (reuses As) for coalesced dwordx4 stores:
// scalar ushort stores were 32B-sector scatter -> 2.5x HBM write amplification.
template<int ACT, int OBF, int BM, int SC, int KS, int VT, int XS>
__global__ __launch_bounds__(512) void bgemm2(const unsigned short* __restrict__ A,
                                              const unsigned short* __restrict__ BT,
                                              const float* __restrict__ bias,
                                              const float* __restrict__ res,
                                              void* __restrict__ Cout,
                                              unsigned short* __restrict__ VtP,
                                              int M, int N, int K) {
    constexpr int MR = BM / 32;        // m-frags per wave (8 or 4)
    constexpr int NR = 4;              // n-frags per wave (64 cols)
    constexpr int WM = BM / 2;         // rows per wave
    constexpr int RA = BM / 64;        // A staging rounds (4 or 2)
    constexpr int RB = 4;              // B staging rounds
    __shared__ __align__(16) unsigned short As[2 * BM * 64];
    __shared__ __align__(16) unsigned short Bs[2 * 256 * 64];
    const int t = threadIdx.x, wv = t >> 6, quad = (t & 63) >> 4, ln15 = t & 15;
    const int wm = wv >> 2, wn = wv & 3;
    int bxi = blockIdx.x, byi = blockIdx.y;
    if (XS) {                           // bijective only when gridDim.x % 8 == 0
        int id = bxi + (int)gridDim.x * byi;
        int nt = (int)gridDim.x, xcd = id & 7, loc = id >> 3;
        int per = nt >> 3;
        bxi = xcd * per + (loc % per);
        byi = loc / per;
    }
    const int m0g = byi * BM, n0g = bxi * 256;

    f32x4 acc[MR][NR];
    #pragma unroll
    for (int mr = 0; mr < MR; ++mr)
        #pragma unroll
        for (int nr = 0; nr < NR; ++nr)
            #pragma unroll
            for (int i = 0; i < 4; ++i) acc[mr][nr][i] = 0.0f;

    const int kbeg = (KS > 1) ? (int)blockIdx.z * (K / KS) : 0;
    const int NT = ((KS > 1) ? K / KS : K) >> 6;

    // per-thread staging sources (swizzled source, linear LDS dest)
    const unsigned short* ap[RA];
    #pragma unroll
    for (int j = 0; j < RA; ++j) {
        int c = j * 512 + t, row = c >> 3, u = (t & 7) ^ (row & 7);
        ap[j] = A + (size_t)(m0g + row) * K + kbeg + u * 8;
    }
    const unsigned short* bp[RB];
    #pragma unroll
    for (int j = 0; j < RB; ++j) {
        int c = j * 512 + t, row = c >> 3, u = (t & 7) ^ (row & 7);
        bp[j] = BT + (size_t)(n0g + row) * K + kbeg + u * 8;
    }

    auto STAGE = [&](int kt, int buf) {
        unsigned short* Ad = As + buf * (BM * 64);
        unsigned short* Bd = Bs + buf * (256 * 64);
        #pragma unroll
        for (int j = 0; j < RA; ++j)
            gl_lds16(ap[j] + (size_t)kt * 64, Ad + (j * 512 + wv * 64) * 8);
        #pragma unroll
        for (int j = 0; j < RB; ++j)
            gl_lds16(bp[j] + (size_t)kt * 64, Bd + (j * 512 + wv * 64) * 8);
    };

    // prologue: tiles 0 and 1 in flight; wait tile 0 only
    STAGE(0, 0);
    STAGE(1, 1);
    if constexpr (RA + RB == 8) VMCNT8(); else VMCNT6();
    __builtin_amdgcn_s_barrier();

    int buf = 0;
    for (int kt = 0; kt < NT; ++kt) {
        const unsigned short* Ab = As + buf * (BM * 64);
        const unsigned short* Bb = Bs + buf * (256 * 64);
        // ---- slice 0 frags + MFMA (compiler inserts its own lgkm waits) ----
        s16x8 a0[MR], b0[NR], a1[MR], b1[NR];
        #pragma unroll
        for (int mr = 0; mr < MR; ++mr) {
            int row = wm * WM + mr * 16 + ln15;
            a0[mr] = *(const s16x8*)&Ab[(row * 8 + (quad ^ (row & 7))) * 8];
        }
        #pragma unroll
        for (int nr = 0; nr < NR; ++nr) {
            int row = wn * 64 + nr * 16 + ln15;
            b0[nr] = *(const s16x8*)&Bb[(row * 8 + (quad ^ (row & 7))) * 8];
        }
        #pragma unroll
        for (int mr = 0; mr < MR; ++mr)
            #pragma unroll
            for (int nr = 0; nr < NR; ++nr)
                acc[mr][nr] = __builtin_amdgcn_mfma_f32_16x16x32_bf16(a0[mr], b0[nr], acc[mr][nr], 0, 0, 0);
        // ---- slice 1 frags ----
        #pragma unroll
        for (int mr = 0; mr < MR; ++mr) {
            int row = wm * WM + mr * 16 + ln15;
            a1[mr] = *(const s16x8*)&Ab[(row * 8 + ((4 + quad) ^ (row & 7))) * 8];
        }
        #pragma unroll
        for (int nr = 0; nr < NR; ++nr) {
            int row = wn * 64 + nr * 16 + ln15;
            b1[nr] = *(const s16x8*)&Bb[(row * 8 + ((4 + quad) ^ (row & 7))) * 8];
        }
        LGKM0();                              // all this-tile LDS reads retired
        __builtin_amdgcn_sched_barrier(0);    // nothing crosses (pin reads above barrier)
        __builtin_amdgcn_s_barrier();         // all waves done reading buf
        if (kt + 2 < NT) STAGE(kt + 2, buf);  // overwrite now-dead buf
        __builtin_amdgcn_s_setprio(1);
        #pragma unroll
        for (int mr = 0; mr < MR; ++mr)
            #pragma unroll
            for (int nr = 0; nr < NR; ++nr)
                acc[mr][nr] = __builtin_amdgcn_mfma_f32_16x16x32_bf16(a1[mr], b1[nr], acc[mr][nr], 0, 0, 0);
        __builtin_amdgcn_s_setprio(0);
        if (kt + 2 < NT) {                    // wait tile kt+1 (leave kt+2 in flight)
            if constexpr (RA + RB == 8) VMCNT8(); else VMCNT6();
            __builtin_amdgcn_s_barrier();
        } else if (kt + 1 < NT) {
            VMCNT0();
            __builtin_amdgcn_s_barrier();
        }
        buf ^= 1;
    }

    const int colb = n0g + wn * 64 + ln15;
    if (KS > 1) {                                   // fp32 partial, no epilogue
        float* P = (float*)Cout + (size_t)blockIdx.z * M * N;
        #pragma unroll
        for (int nr = 0; nr < NR; ++nr) {
            const int col = colb + nr * 16;
            #pragma unroll
            for (int mr = 0; mr < MR; ++mr) {
                const int row0 = m0g + wm * WM + mr * 16 + quad * 4;
                #pragma unroll
                for (int i = 0; i < 4; ++i)
                    P[(size_t)(row0 + i) * N + col] = acc[mr][nr][i];
            }
        }
        return;
    }
    if constexpr (OBF && !VT && BM == 256) {
        if (res == nullptr) {
            // ---- epilogue via LDS (reuses As, 64KB = 128x256 bf16 per half) ----
            // stage: scalar b16 writes, col XOR-swizzled by (row>>2)&3 so the 4
            // quads land on distinct bank groups (2-way max = free).
            // readback: ds_read_b128 + dwordx4 stores, 512B contiguous per row.
            unsigned short* Ep = As;
            unsigned short* Cg = (unsigned short*)Cout;
            #pragma unroll
            for (int half = 0; half < 2; ++half) {
                LGKM0(); __builtin_amdgcn_s_barrier();
                if (wm == half) {
                    #pragma unroll
                    for (int mr = 0; mr < MR; ++mr) {
                        #pragma unroll
                        for (int nr = 0; nr < NR; ++nr) {
                            const int col = wn * 64 + nr * 16 + ln15;
                            const float bv = bias[n0g + col];
                            #pragma unroll
                            for (int i = 0; i < 4; ++i) {
                                const int row = mr * 16 + quad * 4 + i;
                                float v = acc[mr][nr][i] + bv;
                                if (ACT) v = gelu_f(v);
                                if (SC && (n0g + col) < C_) v *= 0.18033688011112042f;
                                Ep[row * 256 + (col ^ (((row >> 2) & 3) << 4))] = f2bf(v);
                            }
                        }
                    }
                }
                LGKM0(); __builtin_amdgcn_s_barrier();
                #pragma unroll
                for (int it = 0; it < 8; ++it) {
                    int off = it * 4096 + t * 8;
                    int row = off >> 8, c0 = off & 255;
                    int sc0 = c0 ^ (((row >> 2) & 3) << 4);
                    s16x8 vld = *(const s16x8*)&Ep[row * 256 + sc0];
                    *(s16x8*)&Cg[(size_t)(m0g + half * 128 + row) * N + n0g + c0] = vld;
                }
            }
            return;
        }
    }
    #pragma unroll
    for (int nr = 0; nr < NR; ++nr) {
        const int col = colb + nr * 16;
        const float bv = bias[col];
        const float sc = (SC && col < C_) ? 0.18033688011112042f : 1.0f;
        if (VT && col >= 2 * C_) {
            const int vcol = col - 2 * C_;
            #pragma unroll
            for (int mr = 0; mr < MR; ++mr) {
                const int row0 = m0g + wm * WM + mr * 16 + quad * 4;
                const int bb = row0 >> 11, l = row0 & (L_ - 1);
                ushort4 pk;
                pk.x = f2bf(acc[mr][nr][0] + bv);
                pk.y = f2bf(acc[mr][nr][1] + bv);
                pk.z = f2bf(acc[mr][nr][2] + bv);
                pk.w = f2bf(acc[mr][nr][3] + bv);
                *(ushort4*)&VtP[(size_t)(bb * 1024 + vcol) * L_ + l] = pk;
            }
        } else {
            #pragma unroll
            for (int mr = 0; mr < MR; ++mr) {
                const int row0 = m0g + wm * WM + mr * 16 + quad * 4;
                #pragma unroll
                for (int i = 0; i < 4; ++i) {
                    float v = acc[mr][nr][i] + bv;
                    if (ACT) v = gelu_f(v);
                    if (SC) v *= sc;
                    size_t off = (size_t)(row0 + i) * N + col;
                    if (res != nullptr) v += res[off];
                    if (OBF) ((unsigned short*)Cout)[off] = f2bf(v);
                    else     ((float*)Cout)[off] = v;
                }
            }
        }
    }
}

// ---------------- combine: out = p0 + p1 + bias + res (fp32) ----------------
__global__ __launch_bounds__(256) void combine_out(const float* __restrict__ p,
                                                   const float* __restrict__ bias,
                                                   const float* __restrict__ res,
                                                   float* __restrict__ out) {
    int idx = blockIdx.x * 256 + threadIdx.x;       // float4 index
    size_t off = (size_t)idx * 4;
    float4 a = *(const float4*)&p[off];
    float4 b = *(const float4*)&p[(size_t)M_ * C_ + off];
    float4 r = *(const float4*)&res[off];
    float4 bb = *(const float4*)&bias[off & (C_ - 1)];
    float4 o;
    o.x = a.x + b.x + r.x + bb.x;
    o.y = a.y + b.y + r.y + bb.y;
    o.z = a.z + b.z + r.z + bb.z;
    o.w = a.w + b.w + r.w + bb.w;
    *(float4*)&out[off] = o;
}

// ---------------- MFMA flash attention, double-buffered K/V, transposed-S ----------------
// Grid 512 blocks (balanced: 2 reps of paired q-tiles = constant 17 K-tiles).
// K/V double-buffered: stage(kt+1) issued at iter top, raw s_barrier + counted
// waits so staging latency hides under the QK->softmax->PV body.
__global__ __launch_bounds__(256) void attn_kernel(const unsigned short* __restrict__ qkv,
                                                   const unsigned short* __restrict__ Vt,
                                                   unsigned short* __restrict__ y) {
    __shared__ __align__(16) unsigned short Qs[64 * 64];        // 8KB; m/l scratch at merge
    __shared__ __align__(16) unsigned short Ks[2 * 128 * 64];   // 32KB; P overlays current buf
    __shared__ __align__(16) unsigned short Vs[2 * 64 * 128];   // 32KB ([d][key])
    const int t = threadIdx.x, w = t >> 6, quad = (t & 63) >> 4, ln15 = t & 15;
    const int wq = w >> 1, wk = w & 1;
    const int id = blockIdx.x;
    const int bh = (id & 7) * 4 + ((id >> 3) & 3);
    const int qpair = id >> 5;
    const int b = bh >> 4, h = bh & 15;

    #pragma unroll 1
    for (int rep = 0; rep < 2; ++rep) {
        const int qt = rep == 0 ? (31 - qpair) : qpair;
        const int q0 = qt * 64;
        if (rep) __syncthreads();            // protect Qs/Ks merge-scratch reuse
        #pragma unroll
        for (int j = 0; j < 2; ++j) {        // stage Q [64 rows][8 units], swizzled
            int c = j * 256 + t;
            int row = c >> 3, u = (c & 7) ^ (row & 7);
            gl_lds16(qkv + (size_t)(b * L_ + q0 + row) * (3*C_) + h * 64 + u * 8,
                     Qs + (j * 256 + w * 64) * 8);
        }
        // stage K/V tile 0 into buf 0
        #pragma unroll
        for (int j = 0; j < 4; ++j) {
            int c = j * 256 + t;
            int row = c >> 3, u = (c & 7) ^ (row & 7);
            gl_lds16(qkv + (size_t)(b * L_ + row) * (3*C_) + C_ + h * 64 + u * 8,
                     Ks + (j * 256 + w * 64) * 8);
        }
        #pragma unroll
        for (int j = 0; j < 4; ++j) {
            int c = j * 256 + t;
            int row = c >> 4, u = (c & 15) ^ (row & 15);
            gl_lds16(Vt + (size_t)(bh * 64 + row) * L_ + u * 8,
                     Vs + (j * 256 + w * 64) * 8);
        }
        __syncthreads();                     // prologue full drain (Q + tile0 ready)

        s16x8 qb[2][2];                      // hoist Q^T B-frags
        #pragma unroll
        for (int qf = 0; qf < 2; ++qf) {
            int row = wq * 32 + qf * 16 + ln15;
            #pragma unroll
            for (int s = 0; s < 2; ++s)
                qb[qf][s] = *(const s16x8*)&Qs[row * 64 + (((s * 4 + quad)) ^ (row & 7)) * 8];
        }

        f32x4 O[4][2];                       // [d-frag][q-frag]
        float m_[2] = {-INFINITY, -INFINITY}, l_[2] = {0.0f, 0.0f};
        #pragma unroll
        for (int df = 0; df < 4; ++df)
            #pragma unroll
            for (int qf = 0; qf < 2; ++qf)
                #pragma unroll
                for (int i = 0; i < 4; ++i) O[df][qf][i] = 0.0f;

        const int nkt = (qt >> 1) + 1;
        int buf = 0;
        for (int kt = 0; kt < nkt; ++kt) {
            unsigned short* Kb = Ks + buf * (128 * 64);
            unsigned short* Vb = Vs + buf * (64 * 128);
            unsigned short* Kn = Ks + (buf ^ 1) * (128 * 64);
            unsigned short* Vn = Vs + (buf ^ 1) * (64 * 128);
            if (kt + 1 < nkt) {              // prefetch next K/V into the other buf
                #pragma unroll
                for (int j = 0; j < 4; ++j) {
                    int c = j * 256 + t;
                    int row = c >> 3, u = (c & 7) ^ (row & 7);
                    gl_lds16(qkv + (size_t)(b * L_ + (kt + 1) * 128 + row) * (3*C_) + C_ + h * 64 + u * 8,
                             Kn + (j * 256 + w * 64) * 8);
                }
                #pragma unroll
                for (int j = 0; j < 4; ++j) {
                    int c = j * 256 + t;
                    int row = c >> 4, u = (c & 15) ^ (row & 15);
                    gl_lds16(Vt + (size_t)(bh * 64 + row) * L_ + (kt + 1) * 128 + u * 8,
                             Vn + (j * 256 + w * 64) * 8);
                }
            }

            // S^T = K Q^T : rows = key, cols = q   (pre-scaled, log2 domain)
            f32x4 St[2][4];
            #pragma unroll
            for (int qf = 0; qf < 2; ++qf)
                #pragma unroll
                for (int kf = 0; kf < 4; ++kf)
                    #pragma unroll
                    for (int i = 0; i < 4; ++i) St[qf][kf][i] = 0.0f;
            #pragma unroll
            for (int s = 0; s < 2; ++s) {
                s16x8 ka[4];
                #pragma unroll
                for (int kf = 0; kf < 4; ++kf) {
                    int row = wk * 64 + kf * 16 + ln15;
                    ka[kf] = *(const s16x8*)&Kb[row * 64 + ((s * 4 + quad) ^ (row & 7)) * 8];
                }
                #pragma unroll
                for (int qf = 0; qf < 2; ++qf)
                    #pragma unroll
                    for (int kf = 0; kf < 4; ++kf)
                        St[qf][kf] = __builtin_amdgcn_mfma_f32_16x16x32_bf16(ka[kf], qb[qf][s], St[qf][kf], 0, 0, 0);
            }
            // all waves' K-frag ds_reads retired before P overwrites Kb.
            // raw barrier: no vmcnt drain -> prefetch stays in flight.
            LGKM0(); SCHED0();
            __builtin_amdgcn_s_barrier();
            SCHED0();

            // online softmax (lane owns q-row = ln15 per frag) + P write (wave-private)
            unsigned short* Pw = Kb + w * 2048;
            const bool diag = (kt == nkt - 1);
            #pragma unroll
            for (int qf = 0; qf < 2; ++qf) {
                const int qg = q0 + wq * 32 + qf * 16 + ln15;
                float mt = -INFINITY;
                if (diag) {
                    #pragma unroll
                    for (int kf = 0; kf < 4; ++kf)
                        #pragma unroll
                        for (int i = 0; i < 4; ++i) {
                            int key = kt * 128 + wk * 64 + kf * 16 + quad * 4 + i;
                            float sv = St[qf][kf][i];
                            sv = (key > qg) ? -INFINITY : sv;
                            St[qf][kf][i] = sv;
                            mt = fmaxf(mt, sv);
                        }
                } else {
                    #pragma unroll
                    for (int kf = 0; kf < 4; ++kf)
                        #pragma unroll
                        for (int i = 0; i < 4; ++i) mt = fmaxf(mt, St[qf][kf][i]);
                }
                mt = fmaxf(mt, __shfl_xor(mt, 16));
                mt = fmaxf(mt, __shfl_xor(mt, 32));
                const float mn = fmaxf(m_[qf], mt);
                const float ms = (mn == -INFINITY) ? 0.0f : mn;  // guard: fully-masked so far
                const float alpha = fexp2(m_[qf] - ms);          // -inf - finite -> 0
                float rs = 0.0f;
                #pragma unroll
                for (int kf = 0; kf < 4; ++kf)
                    #pragma unroll
                    for (int i = 0; i < 4; ++i) {
                        float e = fexp2(St[qf][kf][i] - ms);
                        St[qf][kf][i] = e;
                        rs += e;
                    }
                rs += __shfl_xor(rs, 16);
                rs += __shfl_xor(rs, 32);
                l_[qf] = l_[qf] * alpha + rs;
                m_[qf] = mn;
                #pragma unroll
                for (int df = 0; df < 4; ++df) O[df][qf] *= alpha;
                #pragma unroll
                for (int kf = 0; kf < 4; ++kf) {      // P[q][key] pack via v_perm, b64 writes
                    int row = qf * 16 + ln15;
                    int slot = (kf * 2 + (quad >> 1)) ^ (row & 7);
                    unsigned u0 = __float_as_uint(St[qf][kf][0]) + 0x8000u;
                    unsigned u1 = __float_as_uint(St[qf][kf][1]) + 0x8000u;
                    unsigned u2 = __float_as_uint(St[qf][kf][2]) + 0x8000u;
                    unsigned u3 = __float_as_uint(St[qf][kf][3]) + 0x8000u;
                    uint2 pk;
                    pk.x = __builtin_amdgcn_perm(u1, u0, 0x07060302u);
                    pk.y = __builtin_amdgcn_perm(u3, u2, 0x07060302u);
                    *(uint2*)&Pw[row * 64 + slot * 8 + (quad & 1) * 4] = pk;
                }
            }

            // O^T += V^T P^T  (no barrier: Pw wave-private)
            #pragma unroll
            for (int s2 = 0; s2 < 2; ++s2) {
                s16x8 pb[2], va[4];
                #pragma unroll
                for (int qf = 0; qf < 2; ++qf) {
                    int row = qf * 16 + ln15;
                    pb[qf] = *(const s16x8*)&Pw[row * 64 + ((s2 * 4 + quad) ^ (row & 7)) * 8];
                }
                #pragma unroll
                for (int df = 0; df < 4; ++df) {
                    int row = df * 16 + ln15;
                    int uu = wk * 8 + s2 * 4 + quad;
                    va[df] = *(const s16x8*)&Vb[row * 128 + (uu ^ (row & 15)) * 8];
                }
                #pragma unroll
                for (int df = 0; df < 4; ++df)
                    #pragma unroll
                    for (int qf = 0; qf < 2; ++qf)
                        O[df][qf] = __builtin_amdgcn_mfma_f32_16x16x32_bf16(va[df], pb[qf], O[df][qf], 0, 0, 0);
            }

            if (kt + 1 < nkt) {
                // staged tile kt+1 complete + this iter's LDS ops retired, then
                // release: next iter may overwrite buf^1's former contents.
                LGKM0(); VMCNT0(); SCHED0();
                __builtin_amdgcn_s_barrier();
                SCHED0();
            }
            buf ^= 1;
        }

        // merge the two key-halves (wk=1 publishes, wk=0 combines + stores)
        // OB overlays Ks[0] (dead); slot XOR-swizzled by row to kill the
        // 16-way bank conflict of a linear [rq][64] f32 layout.
        __syncthreads();
        float* OB  = (float*)Ks;             // [64 q][16 f4-slots] f32 = 16KB
        float* MLm = (float*)Qs;             // 64 + 64 floats
        float* MLl = MLm + 64;
        if (wk == 1) {
            #pragma unroll
            for (int qf = 0; qf < 2; ++qf) {
                int rq = wq * 32 + qf * 16 + ln15;
                if (quad == 0) { MLm[rq] = m_[qf]; MLl[rq] = l_[qf]; }
                #pragma unroll
                for (int df = 0; df < 4; ++df) {
                    float4 o;
                    o.x = O[df][qf][0]; o.y = O[df][qf][1]; o.z = O[df][qf][2]; o.w = O[df][qf][3];
                    *(float4*)&OB[rq * 64 + (((df * 4 + quad) ^ (rq & 15)) << 2)] = o;
                }
            }
        }
        __syncthreads();
        if (wk == 0) {
            #pragma unroll
            for (int qf = 0; qf < 2; ++qf) {
                const int rq = wq * 32 + qf * 16 + ln15;
                const float m1 = MLm[rq], l1 = MLl[rq];
                const float mF = fmaxf(m_[qf], m1);
                float e0 = fexp2(m_[qf] - mF);
                float e1 = (m1 == -INFINITY) ? 0.0f : fexp2(m1 - mF);
                const float linv = frcp(l_[qf] * e0 + l1 * e1);
                e0 *= linv; e1 *= linv;
                #pragma unroll
                for (int df = 0; df < 4; ++df) {
                    float4 o1 = *(const float4*)&OB[rq * 64 + (((df * 4 + quad) ^ (rq & 15)) << 2)];
                    ushort4 yv;
                    yv.x = f2bf(O[df][qf][0] * e0 + o1.x * e1);
                    yv.y = f2bf(O[df][qf][1] * e0 + o1.y * e1);
                    yv.z = f2bf(O[df][qf][2] * e0 + o1.z * e1);
                    yv.w = f2bf(O[df][qf][3] * e0 + o1.w * e1);
                    *(ushort4*)&y[(size_t)(b * L_ + q0 + rq) * C_ + h * 64 + df * 16 + quad * 4] = yv;
                }
            }
        }
    }
}

#define MB(x) ((size_t)(x) << 20)

extern "C" void kernel_launch(void* const* d_in, const int* in_sizes, int n_in,
                              void* d_out, int out_size, void* d_ws, size_t ws_size,
                              hipStream_t stream) {
    const float* x      = (const float*)d_in[0];
    const float* ln1_w  = (const float*)d_in[1];
    const float* ln1_b  = (const float*)d_in[2];
    const float* w_attn = (const float*)d_in[3];
    const float* b_attn = (const float*)d_in[4];
    const float* w_proj = (const float*)d_in[5];
    const float* b_proj = (const float*)d_in[6];
    const float* ln2_w  = (const float*)d_in[7];
    const float* ln2_b  = (const float*)d_in[8];
    const float* w_fc   = (const float*)d_in[9];
    const float* b_fc   = (const float*)d_in[10];
    const float* w_fc2  = (const float*)d_in[11];
    const float* b_fc2  = (const float*)d_in[12];
    float* out = (float*)d_out;

    char* ws = (char*)d_ws;
    unsigned short* wT1  = (unsigned short*)(ws + MB(0));   // [3072,1024] 6MB
    unsigned short* wT2  = (unsigned short*)(ws + MB(6));   // [1024,1024] 2MB
    unsigned short* wT3  = (unsigned short*)(ws + MB(8));   // [4096,1024] 8MB
    unsigned short* wT4  = (unsigned short*)(ws + MB(16));  // [1024,4096] 8MB
    unsigned short* h_bf = (unsigned short*)(ws + MB(24));  // [4096,1024] 8MB (h, then h2)
    unsigned short* qkv  = (unsigned short*)(ws + MB(32));  // [4096,3072] 24MB (V third unused)
    unsigned short* Vt   = (unsigned short*)(ws + MB(56));  // [32*64,2048] 8MB (written by qkv GEMM)
    unsigned short* y_bf = (unsigned short*)(ws + MB(64));  // [4096,1024] 8MB
    float*          x1   = (float*)(ws + MB(72));           // [4096,1024] 16MB fp32
    unsigned short* f_bf = (unsigned short*)(ws + MB(88));  // [4096,4096] 32MB
    float*          part = (float*)(ws + MB(32));           // 2x[4096,1024] fp32 = 32MB
                                                            // (reuses dead qkv+Vt region)
    dim3 b256(256), b512(512);

    // weights transpose+cast + LN1 in one launch (independent inputs)
    prep_kernel<<<12288 + M_, b256, 0, stream>>>(w_attn, wT1, w_proj, wT2,
                                                 w_fc, wT3, w_fc2, wT4,
                                                 x, ln1_w, ln1_b, h_bf);
    // qkv = h @ w_attn + b_attn; Q cols pre-scaled by 0.125*log2(e);
    // V third written transposed straight into Vt (fused transpose_v)
    bgemm<0,1,128,1,1,1,0><<<dim3(3*C_/128, M_/128), b256, 0, stream>>>(
        h_bf, wT1, b_attn, nullptr, qkv, Vt, M_, 3*C_, C_);
    attn_kernel<<<512, b256, 0, stream>>>(qkv, Vt, y_bf);
    bgemm<0,0,64,0,1,0,0><<<dim3(C_/64, M_/128), b256, 0, stream>>>(
        y_bf, wT2, b_proj, x, x1, nullptr, M_, C_, C_);
    ln_bf16<<<M_, b256, 0, stream>>>(x1, ln2_w, ln2_b, h_bf);
    // fc: deep-pipelined 256x256 tile, 256 blocks (1/CU), XCD swizzle (16 n-tiles % 8 == 0)
    bgemm2<1,1,256,0,1,0,1><<<dim3(4*C_/256, M_/256), b512, 0, stream>>>(
        h_bf, wT3, b_fc, nullptr, f_bf, nullptr, M_, 4*C_, C_);
    // fc2: deep-pipelined 128x256 tile, K-split=2 -> 256 blocks; fp32 partials
    bgemm2<0,0,128,0,2,0,0><<<dim3(C_/256, M_/128, 2), b512, 0, stream>>>(
        f_bf, wT4, nullptr, nullptr, part, nullptr, M_, C_, 4*C_);
    combine_out<<<(M_*C_)/(4*256), b256, 0, stream>>>(part, b_fc2, x1, out);
}

// Round 6
// 333.240 us; speedup vs baseline: 1.0387x; 1.0387x over previous
//
#include <hip/hip_runtime.h>
#include <math.h>

#define B_ 2
#define L_ 2048
#define C_ 1024
#define H_ 16
#define M_ (B_*L_)   // 4096 rows

typedef short s16x8 __attribute__((ext_vector_type(8)));
typedef float f32x4 __attribute__((ext_vector_type(4)));

__device__ __forceinline__ unsigned short f2bf(float f) {
    unsigned int u = __float_as_uint(f);
    u += 0x7fffu + ((u >> 16) & 1u);      // RNE
    return (unsigned short)(u >> 16);
}

__device__ __forceinline__ float fexp2(float x) {
#if __has_builtin(__builtin_amdgcn_exp2f)
    return __builtin_amdgcn_exp2f(x);     // raw v_exp_f32 (base-2)
#else
    return exp2f(x);
#endif
}

__device__ __forceinline__ float frcp(float x) {
#if __has_builtin(__builtin_amdgcn_rcpf)
    return __builtin_amdgcn_rcpf(x);      // v_rcp_f32
#else
    return 1.0f / x;
#endif
}

__device__ __forceinline__ void gl_lds16(const void* g, void* l) {
    __builtin_amdgcn_global_load_lds(
        (const __attribute__((address_space(1))) void*)g,
        (__attribute__((address_space(3))) void*)l, 16, 0, 0);
}

#define VMCNT8() asm volatile("s_waitcnt vmcnt(8)" ::: "memory")
#define VMCNT6() asm volatile("s_waitcnt vmcnt(6)" ::: "memory")
#define VMCNT0() asm volatile("s_waitcnt vmcnt(0)" ::: "memory")
#define LGKM0()  asm volatile("s_waitcnt lgkmcnt(0)" ::: "memory")
#define SCHED0() __builtin_amdgcn_sched_barrier(0)

// ---------------- LayerNorm row body (shared by prep + ln2) ----------------
__device__ __forceinline__ void ln_row(const float* __restrict__ x,
                                       const float* __restrict__ w,
                                       const float* __restrict__ b,
                                       unsigned short* __restrict__ out,
                                       int row, int t,
                                       float* red0, float* red1, float* mv) {
    float4 v = ((const float4*)(x + (size_t)row * C_))[t];
    float s  = v.x + v.y + v.z + v.w;
    float s2 = v.x*v.x + v.y*v.y + v.z*v.z + v.w*v.w;
    #pragma unroll
    for (int off = 32; off > 0; off >>= 1) {
        s  += __shfl_down(s, off);
        s2 += __shfl_down(s2, off);
    }
    int wave = t >> 6, lane = t & 63;
    if (lane == 0) { red0[wave] = s; red1[wave] = s2; }
    __syncthreads();
    if (t == 0) {
        float a = red0[0] + red0[1] + red0[2] + red0[3];
        float c = red1[0] + red1[1] + red1[2] + red1[3];
        float mean = a * (1.0f / C_);
        mv[0] = mean;
        mv[1] = rsqrtf(c * (1.0f / C_) - mean * mean + 1e-5f);
    }
    __syncthreads();
    float mean = mv[0], rstd = mv[1];
    float4 wv = ((const float4*)w)[t];
    float4 bv = ((const float4*)b)[t];
    ushort4 o;
    o.x = f2bf((v.x - mean) * rstd * wv.x + bv.x);
    o.y = f2bf((v.y - mean) * rstd * wv.y + bv.y);
    o.z = f2bf((v.z - mean) * rstd * wv.z + bv.z);
    o.w = f2bf((v.w - mean) * rstd * wv.w + bv.w);
    *(ushort4*)&out[(size_t)row * C_ + t * 4] = o;
}

__global__ __launch_bounds__(256) void ln_bf16(const float* __restrict__ x,
                                               const float* __restrict__ w,
                                               const float* __restrict__ b,
                                               unsigned short* __restrict__ out) {
    __shared__ float red0[4], red1[4], mv[2];
    ln_row(x, w, b, out, blockIdx.x, threadIdx.x, red0, red1, mv);
}

// ---------------- prep: 4-way weight transpose+cast  +  LN1 (independent inputs) ----------------
__global__ __launch_bounds__(256) void prep_kernel(
    const float* __restrict__ W0, unsigned short* __restrict__ T0,
    const float* __restrict__ W1, unsigned short* __restrict__ T1,
    const float* __restrict__ W2, unsigned short* __restrict__ T2,
    const float* __restrict__ W3, unsigned short* __restrict__ T3,
    const float* __restrict__ x, const float* __restrict__ lnw,
    const float* __restrict__ lnb, unsigned short* __restrict__ h) {
    __shared__ unsigned short Ts[32][33];
    __shared__ float red0[4], red1[4], mv[2];
    int id = blockIdx.x;
    int t = threadIdx.x;
    if (id >= 12288) {                       // LN1 rows
        ln_row(x, lnw, lnb, h, id - 12288, t, red0, red1, mv);
        return;
    }
    const float* W; unsigned short* WT; int R, C, bx, by;
    if (id < 3072)      { W = W0; WT = T0; R = 1024; C = 3072; bx = id % 96;  by = id / 96; }
    else if (id < 4096) { W = W1; WT = T1; R = 1024; C = 1024; id -= 3072; bx = id & 31;  by = id >> 5; }
    else if (id < 8192) { W = W2; WT = T2; R = 1024; C = 4096; id -= 4096; bx = id & 127; by = id >> 7; }
    else                { W = W3; WT = T3; R = 4096; C = 1024; id -= 8192; bx = id & 31;  by = id >> 5; }
    int tx = t & 31, ty = t >> 5;
    int c0 = bx * 32, r0 = by * 32;
    #pragma unroll
    for (int k = 0; k < 4; ++k)
        Ts[ty + 8*k][tx] = f2bf(W[(size_t)(r0 + ty + 8*k) * C + c0 + tx]);
    __syncthreads();
    #pragma unroll
    for (int k = 0; k < 4; ++k)
        WT[(size_t)(c0 + ty + 8*k) * R + r0 + tx] = Ts[tx][ty + 8*k];
}

// ---------------- bf16 MFMA GEMM, BK=64 (legacy 2-barrier 128-tile) ----------------
__device__ __forceinline__ float gelu_f(float x) {
    // 0.5x(1+tanh(u)) = x / (1 + exp(-2u)); overflow-safe both directions
    float u2 = 1.5957691216057308f * (x + 0.044715f * x * x * x);
    return x * frcp(1.0f + __expf(-u2));
}

// TN = 128 (waves 2x2, 64x64 each) or 64 (waves 2x2, 64x32 each). BK=64.
template<int ACT, int OBF, int TN, int SC, int KS, int VT, int XS>
__global__ __launch_bounds__(256) void bgemm(const unsigned short* __restrict__ A,
                                             const unsigned short* __restrict__ BT,
                                             const float* __restrict__ bias,
                                             const float* __restrict__ res,
                                             void* __restrict__ Cout,
                                             unsigned short* __restrict__ VtP,
                                             int M, int N, int K) {
    __shared__ __align__(16) unsigned short As[128 * 64];   // 16KB
    __shared__ __align__(16) unsigned short Bs[TN * 64];    // 16/8KB
    const int t = threadIdx.x, w = t >> 6, quad = (t & 63) >> 4, ln15 = t & 15;
    constexpr int FJ = TN / 32;
    const int woff_m = (w >> 1) * 64, woff_n = (w & 1) * (TN / 2);
    int bxi = blockIdx.x, byi = blockIdx.y;
    if (XS) {
        int id = bxi + (int)gridDim.x * byi;
        int nt = (int)gridDim.x, xcd = id & 7, loc = id >> 3;
        int per = (nt + 7) >> 3;
        bxi = xcd * per + (loc % per);
        byi = loc / per;
        if (bxi >= nt) { bxi = id % nt; byi = id / nt; }
    }
    const int m0g = byi * 128, n0g = bxi * TN;
    f32x4 acc[4][FJ];
    #pragma unroll
    for (int fi = 0; fi < 4; ++fi)
        #pragma unroll
        for (int fj = 0; fj < FJ; ++fj)
            #pragma unroll
            for (int i = 0; i < 4; ++i) acc[fi][fj][i] = 0.0f;

    const int kbeg = (KS > 1) ? (int)blockIdx.z * (K / KS) : 0;
    const int kiters = ((KS > 1) ? K / KS : K) >> 6;

    const unsigned short* ap[4];
    #pragma unroll
    for (int j = 0; j < 4; ++j) {
        int c = j * 256 + t, row = c >> 3, u = (c & 7) ^ (row & 7);
        ap[j] = A + (size_t)(m0g + row) * K + kbeg + u * 8;
    }
    const unsigned short* bp[FJ];
    #pragma unroll
    for (int j = 0; j < FJ; ++j) {
        int c = j * 256 + t, row = c >> 3, u = (c & 7) ^ (row & 7);
        bp[j] = BT + (size_t)(n0g + row) * K + kbeg + u * 8;
    }

    for (int kk = 0; kk < kiters; ++kk) {
        __syncthreads();
        #pragma unroll
        for (int j = 0; j < 4; ++j) {
            gl_lds16(ap[j], As + (j * 256 + w * 64) * 8);
            ap[j] += 64;
        }
        #pragma unroll
        for (int j = 0; j < FJ; ++j) {
            gl_lds16(bp[j], Bs + (j * 256 + w * 64) * 8);
            bp[j] += 64;
        }
        __syncthreads();
        #pragma unroll
        for (int s = 0; s < 2; ++s) {
            s16x8 af[4], bfr[FJ];
            #pragma unroll
            for (int f = 0; f < 4; ++f) {
                int row = woff_m + f * 16 + ln15;
                af[f] = *(const s16x8*)&As[(row * 8 + ((s * 4 + quad) ^ (row & 7))) * 8];
            }
            #pragma unroll
            for (int f = 0; f < FJ; ++f) {
                int row = woff_n + f * 16 + ln15;
                bfr[f] = *(const s16x8*)&Bs[(row * 8 + ((s * 4 + quad) ^ (row & 7))) * 8];
            }
            #pragma unroll
            for (int fi = 0; fi < 4; ++fi)
                #pragma unroll
                for (int fj = 0; fj < FJ; ++fj)
                    acc[fi][fj] = __builtin_amdgcn_mfma_f32_16x16x32_bf16(af[fi], bfr[fj], acc[fi][fj], 0, 0, 0);
        }
    }

    const int colb = n0g + woff_n + ln15;
    if (KS > 1) {
        float* P = (float*)Cout + (size_t)blockIdx.z * M * N;
        #pragma unroll
        for (int fj = 0; fj < FJ; ++fj) {
            const int col = colb + fj * 16;
            #pragma unroll
            for (int fi = 0; fi < 4; ++fi) {
                const int row0 = m0g + woff_m + fi * 16 + quad * 4;
                #pragma unroll
                for (int i = 0; i < 4; ++i)
                    P[(size_t)(row0 + i) * N + col] = acc[fi][fj][i];
            }
        }
        return;
    }
    #pragma unroll
    for (int fj = 0; fj < FJ; ++fj) {
        const int col = colb + fj * 16;
        const float bv = bias[col];
        const float sc = (SC && col < C_) ? 0.18033688011112042f : 1.0f;
        if (VT && col >= 2 * C_) {
            const int vcol = col - 2 * C_;
            #pragma unroll
            for (int fi = 0; fi < 4; ++fi) {
                const int row0 = m0g + woff_m + fi * 16 + quad * 4;
                const int bb = row0 >> 11, l = row0 & (L_ - 1);
                ushort4 pk;
                pk.x = f2bf(acc[fi][fj][0] + bv);
                pk.y = f2bf(acc[fi][fj][1] + bv);
                pk.z = f2bf(acc[fi][fj][2] + bv);
                pk.w = f2bf(acc[fi][fj][3] + bv);
                *(ushort4*)&VtP[(size_t)(bb * 1024 + vcol) * L_ + l] = pk;
            }
        } else {
            #pragma unroll
            for (int fi = 0; fi < 4; ++fi) {
                const int row0 = m0g + woff_m + fi * 16 + quad * 4;
                #pragma unroll
                for (int i = 0; i < 4; ++i) {
                    float v = acc[fi][fj][i] + bv;
                    if (ACT) v = gelu_f(v);
                    if (SC) v *= sc;
                    size_t off = (size_t)(row0 + i) * N + col;
                    if (res != nullptr) v += res[off];
                    if (OBF) ((unsigned short*)Cout)[off] = f2bf(v);
                    else     ((float*)Cout)[off] = v;
                }
            }
        }
    }
}

// ---------------- bgemm2: deep-pipelined BMx256 tile, BK=64, 512 thr, dbuf LDS ----------------
// One barrier per K-tile; next-next tile prefetch issued right after the barrier;
// counted vmcnt (never 0 in steady state); setprio around 2nd MFMA cluster.
// BM=256: LDS 128KB, waves 2x4 of 128x64. BM=128: LDS 96KB, waves 2x4 of 64x64.
// OBF epilogue goes through LDS (reuses As) for coalesced dwordx4 stores.
// XS=1: n-chunk XCD swizzle (needs gridDim.x % 8 == 0).
// XS=2: flat (x,y,z) remap with gridDim.x*gridDim.z == 8 -> each XCD owns one
//       (n-tile, K-half) combo: B strip stays L2-resident, A streams once.
template<int ACT, int OBF, int BM, int SC, int KS, int VT, int XS>
__global__ __launch_bounds__(512) void bgemm2(const unsigned short* __restrict__ A,
                                              const unsigned short* __restrict__ BT,
                                              const float* __restrict__ bias,
                                              const float* __restrict__ res,
                                              void* __restrict__ Cout,
                                              unsigned short* __restrict__ VtP,
                                              int M, int N, int K) {
    constexpr int MR = BM / 32;        // m-frags per wave (8 or 4)
    constexpr int NR = 4;              // n-frags per wave (64 cols)
    constexpr int WM = BM / 2;         // rows per wave
    constexpr int RA = BM / 64;        // A staging rounds (4 or 2)
    constexpr int RB = 4;              // B staging rounds
    __shared__ __align__(16) unsigned short As[2 * BM * 64];
    __shared__ __align__(16) unsigned short Bs[2 * 256 * 64];
    const int t = threadIdx.x, wv = t >> 6, quad = (t & 63) >> 4, ln15 = t & 15;
    const int wm = wv >> 2, wn = wv & 3;
    int bxi = blockIdx.x, byi = blockIdx.y, bzi = blockIdx.z;
    if (XS == 1) {                      // bijective only when gridDim.x % 8 == 0
        int id = bxi + (int)gridDim.x * byi;
        int nt = (int)gridDim.x, xcd = id & 7, loc = id >> 3;
        int per = nt >> 3;
        bxi = xcd * per + (loc % per);
        byi = loc / per;
    } else if (XS == 2) {               // gridDim.x * gridDim.z == 8
        int gx = (int)gridDim.x;
        int id = bxi + gx * byi + (int)(gridDim.x * gridDim.y) * bzi;
        int xcd = id & 7;
        bxi = xcd % gx;
        bzi = xcd / gx;
        byi = id >> 3;
    }
    const int m0g = byi * BM, n0g = bxi * 256;

    f32x4 acc[MR][NR];
    #pragma unroll
    for (int mr = 0; mr < MR; ++mr)
        #pragma unroll
        for (int nr = 0; nr < NR; ++nr)
            #pragma unroll
            for (int i = 0; i < 4; ++i) acc[mr][nr][i] = 0.0f;

    const int kbeg = (KS > 1) ? bzi * (K / KS) : 0;
    const int NT = ((KS > 1) ? K / KS : K) >> 6;

    // per-thread staging sources (swizzled source, linear LDS dest)
    const unsigned short* ap[RA];
    #pragma unroll
    for (int j = 0; j < RA; ++j) {
        int c = j * 512 + t, row = c >> 3, u = (t & 7) ^ (row & 7);
        ap[j] = A + (size_t)(m0g + row) * K + kbeg + u * 8;
    }
    const unsigned short* bp[RB];
    #pragma unroll
    for (int j = 0; j < RB; ++j) {
        int c = j * 512 + t, row = c >> 3, u = (t & 7) ^ (row & 7);
        bp[j] = BT + (size_t)(n0g + row) * K + kbeg + u * 8;
    }

    auto STAGE = [&](int kt, int buf) {
        unsigned short* Ad = As + buf * (BM * 64);
        unsigned short* Bd = Bs + buf * (256 * 64);
        #pragma unroll
        for (int j = 0; j < RA; ++j)
            gl_lds16(ap[j] + (size_t)kt * 64, Ad + (j * 512 + wv * 64) * 8);
        #pragma unroll
        for (int j = 0; j < RB; ++j)
            gl_lds16(bp[j] + (size_t)kt * 64, Bd + (j * 512 + wv * 64) * 8);
    };

    // prologue: tiles 0 and 1 in flight; wait tile 0 only
    STAGE(0, 0);
    STAGE(1, 1);
    if constexpr (RA + RB == 8) VMCNT8(); else VMCNT6();
    __builtin_amdgcn_s_barrier();

    int buf = 0;
    for (int kt = 0; kt < NT; ++kt) {
        const unsigned short* Ab = As + buf * (BM * 64);
        const unsigned short* Bb = Bs + buf * (256 * 64);
        // ---- slice 0 frags + MFMA (compiler inserts its own lgkm waits) ----
        s16x8 a0[MR], b0[NR], a1[MR], b1[NR];
        #pragma unroll
        for (int mr = 0; mr < MR; ++mr) {
            int row = wm * WM + mr * 16 + ln15;
            a0[mr] = *(const s16x8*)&Ab[(row * 8 + (quad ^ (row & 7))) * 8];
        }
        #pragma unroll
        for (int nr = 0; nr < NR; ++nr) {
            int row = wn * 64 + nr * 16 + ln15;
            b0[nr] = *(const s16x8*)&Bb[(row * 8 + (quad ^ (row & 7))) * 8];
        }
        #pragma unroll
        for (int mr = 0; mr < MR; ++mr)
            #pragma unroll
            for (int nr = 0; nr < NR; ++nr)
                acc[mr][nr] = __builtin_amdgcn_mfma_f32_16x16x32_bf16(a0[mr], b0[nr], acc[mr][nr], 0, 0, 0);
        // ---- slice 1 frags ----
        #pragma unroll
        for (int mr = 0; mr < MR; ++mr) {
            int row = wm * WM + mr * 16 + ln15;
            a1[mr] = *(const s16x8*)&Ab[(row * 8 + ((4 + quad) ^ (row & 7))) * 8];
        }
        #pragma unroll
        for (int nr = 0; nr < NR; ++nr) {
            int row = wn * 64 + nr * 16 + ln15;
            b1[nr] = *(const s16x8*)&Bb[(row * 8 + ((4 + quad) ^ (row & 7))) * 8];
        }
        LGKM0();                              // all this-tile LDS reads retired
        __builtin_amdgcn_sched_barrier(0);    // nothing crosses (pin reads above barrier)
        __builtin_amdgcn_s_barrier();         // all waves done reading buf
        if (kt + 2 < NT) STAGE(kt + 2, buf);  // overwrite now-dead buf
        __builtin_amdgcn_s_setprio(1);
        #pragma unroll
        for (int mr = 0; mr < MR; ++mr)
            #pragma unroll
            for (int nr = 0; nr < NR; ++nr)
                acc[mr][nr] = __builtin_amdgcn_mfma_f32_16x16x32_bf16(a1[mr], b1[nr], acc[mr][nr], 0, 0, 0);
        __builtin_amdgcn_s_setprio(0);
        if (kt + 2 < NT) {                    // wait tile kt+1 (leave kt+2 in flight)
            if constexpr (RA + RB == 8) VMCNT8(); else VMCNT6();
            __builtin_amdgcn_s_barrier();
        } else if (kt + 1 < NT) {
            VMCNT0();
            __builtin_amdgcn_s_barrier();
        }
        buf ^= 1;
    }

    const int colb = n0g + wn * 64 + ln15;
    if (KS > 1) {                                   // fp32 partial, no epilogue
        float* P = (float*)Cout + (size_t)bzi * M * N;
        #pragma unroll
        for (int nr = 0; nr < NR; ++nr) {
            const int col = colb + nr * 16;
            #pragma unroll
            for (int mr = 0; mr < MR; ++mr) {
                const int row0 = m0g + wm * WM + mr * 16 + quad * 4;
                #pragma unroll
                for (int i = 0; i < 4; ++i)
                    P[(size_t)(row0 + i) * N + col] = acc[mr][nr][i];
            }
        }
        return;
    }
    if constexpr (OBF && !VT && BM == 256) {
        if (res == nullptr) {
            // ---- epilogue via LDS (reuses As, 64KB = 128x256 bf16 per half) ----
            // stage: scalar b16 writes, col XOR-swizzled by (row>>2)&3 so the 4
            // quads land on distinct bank groups (2-way max = free).
            // readback: ds_read_b128 + dwordx4 stores, 512B contiguous per row.
            unsigned short* Ep = As;
            unsigned short* Cg = (unsigned short*)Cout;
            #pragma unroll
            for (int half = 0; half < 2; ++half) {
                LGKM0(); __builtin_amdgcn_s_barrier();
                if (wm == half) {
                    #pragma unroll
                    for (int mr = 0; mr < MR; ++mr) {
                        #pragma unroll
                        for (int nr = 0; nr < NR; ++nr) {
                            const int col = wn * 64 + nr * 16 + ln15;
                            const float bv = bias[n0g + col];
                            #pragma unroll
                            for (int i = 0; i < 4; ++i) {
                                const int row = mr * 16 + quad * 4 + i;
                                float v = acc[mr][nr][i] + bv;
                                if (ACT) v = gelu_f(v);
                                if (SC && (n0g + col) < C_) v *= 0.18033688011112042f;
                                Ep[row * 256 + (col ^ (((row >> 2) & 3) << 4))] = f2bf(v);
                            }
                        }
                    }
                }
                LGKM0(); __builtin_amdgcn_s_barrier();
                #pragma unroll
                for (int it = 0; it < 8; ++it) {
                    int off = it * 4096 + t * 8;
                    int row = off >> 8, c0 = off & 255;
                    int sc0 = c0 ^ (((row >> 2) & 3) << 4);
                    s16x8 vld = *(const s16x8*)&Ep[row * 256 + sc0];
                    *(s16x8*)&Cg[(size_t)(m0g + half * 128 + row) * N + n0g + c0] = vld;
                }
            }
            return;
        }
    }
    #pragma unroll
    for (int nr = 0; nr < NR; ++nr) {
        const int col = colb + nr * 16;
        const float bv = bias[col];
        const float sc = (SC && col < C_) ? 0.18033688011112042f : 1.0f;
        if (VT && col >= 2 * C_) {
            const int vcol = col - 2 * C_;
            #pragma unroll
            for (int mr = 0; mr < MR; ++mr) {
                const int row0 = m0g + wm * WM + mr * 16 + quad * 4;
                const int bb = row0 >> 11, l = row0 & (L_ - 1);
                ushort4 pk;
                pk.x = f2bf(acc[mr][nr][0] + bv);
                pk.y = f2bf(acc[mr][nr][1] + bv);
                pk.z = f2bf(acc[mr][nr][2] + bv);
                pk.w = f2bf(acc[mr][nr][3] + bv);
                *(ushort4*)&VtP[(size_t)(bb * 1024 + vcol) * L_ + l] = pk;
            }
        } else {
            #pragma unroll
            for (int mr = 0; mr < MR; ++mr) {
                const int row0 = m0g + wm * WM + mr * 16 + quad * 4;
                #pragma unroll
                for (int i = 0; i < 4; ++i) {
                    float v = acc[mr][nr][i] + bv;
                    if (ACT) v = gelu_f(v);
                    if (SC) v *= sc;
                    size_t off = (size_t)(row0 + i) * N + col;
                    if (res != nullptr) v += res[off];
                    if (OBF) ((unsigned short*)Cout)[off] = f2bf(v);
                    else     ((float*)Cout)[off] = v;
                }
            }
        }
    }
}

// ---------------- combine: out = p0 + p1 + bias + res (fp32) ----------------
__global__ __launch_bounds__(256) void combine_out(const float* __restrict__ p,
                                                   const float* __restrict__ bias,
                                                   const float* __restrict__ res,
                                                   float* __restrict__ out) {
    int idx = blockIdx.x * 256 + threadIdx.x;       // float4 index
    size_t off = (size_t)idx * 4;
    float4 a = *(const float4*)&p[off];
    float4 b = *(const float4*)&p[(size_t)M_ * C_ + off];
    float4 r = *(const float4*)&res[off];
    float4 bb = *(const float4*)&bias[off & (C_ - 1)];
    float4 o;
    o.x = a.x + b.x + r.x + bb.x;
    o.y = a.y + b.y + r.y + bb.y;
    o.z = a.z + b.z + r.z + bb.z;
    o.w = a.w + b.w + r.w + bb.w;
    *(float4*)&out[off] = o;
}

// ---------------- MFMA flash attention, double-buffered K/V, transposed-S ----------------
// Grid 512 blocks (balanced: 2 reps of paired q-tiles = constant 17 K-tiles).
// K/V double-buffered: stage(kt+1) issued at iter top, raw s_barrier + counted
// waits so staging latency hides under the QK->softmax->PV body.
__global__ __launch_bounds__(256) void attn_kernel(const unsigned short* __restrict__ qkv,
                                                   const unsigned short* __restrict__ Vt,
                                                   unsigned short* __restrict__ y) {
    __shared__ __align__(16) unsigned short Qs[64 * 64];        // 8KB; m/l scratch at merge
    __shared__ __align__(16) unsigned short Ks[2 * 128 * 64];   // 32KB; P overlays current buf
    __shared__ __align__(16) unsigned short Vs[2 * 64 * 128];   // 32KB ([d][key])
    const int t = threadIdx.x, w = t >> 6, quad = (t & 63) >> 4, ln15 = t & 15;
    const int wq = w >> 1, wk = w & 1;
    const int id = blockIdx.x;
    const int bh = (id & 7) * 4 + ((id >> 3) & 3);
    const int qpair = id >> 5;
    const int b = bh >> 4, h = bh & 15;

    #pragma unroll 1
    for (int rep = 0; rep < 2; ++rep) {
        const int qt = rep == 0 ? (31 - qpair) : qpair;
        const int q0 = qt * 64;
        if (rep) __syncthreads();            // protect Qs/Ks merge-scratch reuse
        #pragma unroll
        for (int j = 0; j < 2; ++j) {        // stage Q [64 rows][8 units], swizzled
            int c = j * 256 + t;
            int row = c >> 3, u = (c & 7) ^ (row & 7);
            gl_lds16(qkv + (size_t)(b * L_ + q0 + row) * (3*C_) + h * 64 + u * 8,
                     Qs + (j * 256 + w * 64) * 8);
        }
        // stage K/V tile 0 into buf 0
        #pragma unroll
        for (int j = 0; j < 4; ++j) {
            int c = j * 256 + t;
            int row = c >> 3, u = (c & 7) ^ (row & 7);
            gl_lds16(qkv + (size_t)(b * L_ + row) * (3*C_) + C_ + h * 64 + u * 8,
                     Ks + (j * 256 + w * 64) * 8);
        }
        #pragma unroll
        for (int j = 0; j < 4; ++j) {
            int c = j * 256 + t;
            int row = c >> 4, u = (c & 15) ^ (row & 15);
            gl_lds16(Vt + (size_t)(bh * 64 + row) * L_ + u * 8,
                     Vs + (j * 256 + w * 64) * 8);
        }
        __syncthreads();                     // prologue full drain (Q + tile0 ready)

        s16x8 qb[2][2];                      // hoist Q^T B-frags
        #pragma unroll
        for (int qf = 0; qf < 2; ++qf) {
            int row = wq * 32 + qf * 16 + ln15;
            #pragma unroll
            for (int s = 0; s < 2; ++s)
                qb[qf][s] = *(const s16x8*)&Qs[row * 64 + (((s * 4 + quad)) ^ (row & 7)) * 8];
        }

        f32x4 O[4][2];                       // [d-frag][q-frag]
        float m_[2] = {-INFINITY, -INFINITY}, l_[2] = {0.0f, 0.0f};
        #pragma unroll
        for (int df = 0; df < 4; ++df)
            #pragma unroll
            for (int qf = 0; qf < 2; ++qf)
                #pragma unroll
                for (int i = 0; i < 4; ++i) O[df][qf][i] = 0.0f;

        const int nkt = (qt >> 1) + 1;
        int buf = 0;
        for (int kt = 0; kt < nkt; ++kt) {
            unsigned short* Kb = Ks + buf * (128 * 64);
            unsigned short* Vb = Vs + buf * (64 * 128);
            unsigned short* Kn = Ks + (buf ^ 1) * (128 * 64);
            unsigned short* Vn = Vs + (buf ^ 1) * (64 * 128);
            if (kt + 1 < nkt) {              // prefetch next K/V into the other buf
                #pragma unroll
                for (int j = 0; j < 4; ++j) {
                    int c = j * 256 + t;
                    int row = c >> 3, u = (c & 7) ^ (row & 7);
                    gl_lds16(qkv + (size_t)(b * L_ + (kt + 1) * 128 + row) * (3*C_) + C_ + h * 64 + u * 8,
                             Kn + (j * 256 + w * 64) * 8);
                }
                #pragma unroll
                for (int j = 0; j < 4; ++j) {
                    int c = j * 256 + t;
                    int row = c >> 4, u = (c & 15) ^ (row & 15);
                    gl_lds16(Vt + (size_t)(bh * 64 + row) * L_ + (kt + 1) * 128 + u * 8,
                             Vn + (j * 256 + w * 64) * 8);
                }
            }

            // S^T = K Q^T : rows = key, cols = q   (pre-scaled, log2 domain)
            f32x4 St[2][4];
            #pragma unroll
            for (int qf = 0; qf < 2; ++qf)
                #pragma unroll
                for (int kf = 0; kf < 4; ++kf)
                    #pragma unroll
                    for (int i = 0; i < 4; ++i) St[qf][kf][i] = 0.0f;
            #pragma unroll
            for (int s = 0; s < 2; ++s) {
                s16x8 ka[4];
                #pragma unroll
                for (int kf = 0; kf < 4; ++kf) {
                    int row = wk * 64 + kf * 16 + ln15;
                    ka[kf] = *(const s16x8*)&Kb[row * 64 + ((s * 4 + quad) ^ (row & 7)) * 8];
                }
                #pragma unroll
                for (int qf = 0; qf < 2; ++qf)
                    #pragma unroll
                    for (int kf = 0; kf < 4; ++kf)
                        St[qf][kf] = __builtin_amdgcn_mfma_f32_16x16x32_bf16(ka[kf], qb[qf][s], St[qf][kf], 0, 0, 0);
            }
            // all waves' K-frag ds_reads retired before P overwrites Kb.
            // raw barrier: no vmcnt drain -> prefetch stays in flight.
            LGKM0(); SCHED0();
            __builtin_amdgcn_s_barrier();
            SCHED0();

            // online softmax (lane owns q-row = ln15 per frag) + P write (wave-private)
            unsigned short* Pw = Kb + w * 2048;
            const bool diag = (kt == nkt - 1);
            #pragma unroll
            for (int qf = 0; qf < 2; ++qf) {
                const int qg = q0 + wq * 32 + qf * 16 + ln15;
                float mt = -INFINITY;
                if (diag) {
                    #pragma unroll
                    for (int kf = 0; kf < 4; ++kf)
                        #pragma unroll
                        for (int i = 0; i < 4; ++i) {
                            int key = kt * 128 + wk * 64 + kf * 16 + quad * 4 + i;
                            float sv = St[qf][kf][i];
                            sv = (key > qg) ? -INFINITY : sv;
                            St[qf][kf][i] = sv;
                            mt = fmaxf(mt, sv);
                        }
                } else {
                    #pragma unroll
                    for (int kf = 0; kf < 4; ++kf)
                        #pragma unroll
                        for (int i = 0; i < 4; ++i) mt = fmaxf(mt, St[qf][kf][i]);
                }
                mt = fmaxf(mt, __shfl_xor(mt, 16));
                mt = fmaxf(mt, __shfl_xor(mt, 32));
                const float mn = fmaxf(m_[qf], mt);
                const float ms = (mn == -INFINITY) ? 0.0f : mn;  // guard: fully-masked so far
                const float alpha = fexp2(m_[qf] - ms);          // -inf - finite -> 0
                float rs = 0.0f;
                #pragma unroll
                for (int kf = 0; kf < 4; ++kf)
                    #pragma unroll
                    for (int i = 0; i < 4; ++i) {
                        float e = fexp2(St[qf][kf][i] - ms);
                        St[qf][kf][i] = e;
                        rs += e;
                    }
                rs += __shfl_xor(rs, 16);
                rs += __shfl_xor(rs, 32);
                l_[qf] = l_[qf] * alpha + rs;
                m_[qf] = mn;
                #pragma unroll
                for (int df = 0; df < 4; ++df) O[df][qf] *= alpha;
                #pragma unroll
                for (int kf = 0; kf < 4; ++kf) {      // P[q][key] pack via v_perm, b64 writes
                    int row = qf * 16 + ln15;
                    int slot = (kf * 2 + (quad >> 1)) ^ (row & 7);
                    unsigned u0 = __float_as_uint(St[qf][kf][0]) + 0x8000u;
                    unsigned u1 = __float_as_uint(St[qf][kf][1]) + 0x8000u;
                    unsigned u2 = __float_as_uint(St[qf][kf][2]) + 0x8000u;
                    unsigned u3 = __float_as_uint(St[qf][kf][3]) + 0x8000u;
                    uint2 pk;
                    pk.x = __builtin_amdgcn_perm(u1, u0, 0x07060302u);
                    pk.y = __builtin_amdgcn_perm(u3, u2, 0x07060302u);
                    *(uint2*)&Pw[row * 64 + slot * 8 + (quad & 1) * 4] = pk;
                }
            }

            // O^T += V^T P^T  (no barrier: Pw wave-private)
            #pragma unroll
            for (int s2 = 0; s2 < 2; ++s2) {
                s16x8 pb[2], va[4];
                #pragma unroll
                for (int qf = 0; qf < 2; ++qf) {
                    int row = qf * 16 + ln15;
                    pb[qf] = *(const s16x8*)&Pw[row * 64 + ((s2 * 4 + quad) ^ (row & 7)) * 8];
                }
                #pragma unroll
                for (int df = 0; df < 4; ++df) {
                    int row = df * 16 + ln15;
                    int uu = wk * 8 + s2 * 4 + quad;
                    va[df] = *(const s16x8*)&Vb[row * 128 + (uu ^ (row & 15)) * 8];
                }
                #pragma unroll
                for (int df = 0; df < 4; ++df)
                    #pragma unroll
                    for (int qf = 0; qf < 2; ++qf)
                        O[df][qf] = __builtin_amdgcn_mfma_f32_16x16x32_bf16(va[df], pb[qf], O[df][qf], 0, 0, 0);
            }

            if (kt + 1 < nkt) {
                // staged tile kt+1 complete + this iter's LDS ops retired, then
                // release: next iter may overwrite buf^1's former contents.
                LGKM0(); VMCNT0(); SCHED0();
                __builtin_amdgcn_s_barrier();
                SCHED0();
            }
            buf ^= 1;
        }

        // merge the two key-halves (wk=1 publishes, wk=0 combines + stores)
        // OB overlays Ks[0] (dead); slot XOR-swizzled by row to kill the
        // 16-way bank conflict of a linear [rq][64] f32 layout.
        __syncthreads();
        float* OB  = (float*)Ks;             // [64 q][16 f4-slots] f32 = 16KB
        float* MLm = (float*)Qs;             // 64 + 64 floats
        float* MLl = MLm + 64;
        if (wk == 1) {
            #pragma unroll
            for (int qf = 0; qf < 2; ++qf) {
                int rq = wq * 32 + qf * 16 + ln15;
                if (quad == 0) { MLm[rq] = m_[qf]; MLl[rq] = l_[qf]; }
                #pragma unroll
                for (int df = 0; df < 4; ++df) {
                    float4 o;
                    o.x = O[df][qf][0]; o.y = O[df][qf][1]; o.z = O[df][qf][2]; o.w = O[df][qf][3];
                    *(float4*)&OB[rq * 64 + (((df * 4 + quad) ^ (rq & 15)) << 2)] = o;
                }
            }
        }
        __syncthreads();
        if (wk == 0) {
            #pragma unroll
            for (int qf = 0; qf < 2; ++qf) {
                const int rq = wq * 32 + qf * 16 + ln15;
                const float m1 = MLm[rq], l1 = MLl[rq];
                const float mF = fmaxf(m_[qf], m1);
                float e0 = fexp2(m_[qf] - mF);
                float e1 = (m1 == -INFINITY) ? 0.0f : fexp2(m1 - mF);
                const float linv = frcp(l_[qf] * e0 + l1 * e1);
                e0 *= linv; e1 *= linv;
                #pragma unroll
                for (int df = 0; df < 4; ++df) {
                    float4 o1 = *(const float4*)&OB[rq * 64 + (((df * 4 + quad) ^ (rq & 15)) << 2)];
                    ushort4 yv;
                    yv.x = f2bf(O[df][qf][0] * e0 + o1.x * e1);
                    yv.y = f2bf(O[df][qf][1] * e0 + o1.y * e1);
                    yv.z = f2bf(O[df][qf][2] * e0 + o1.z * e1);
                    yv.w = f2bf(O[df][qf][3] * e0 + o1.w * e1);
                    *(ushort4*)&y[(size_t)(b * L_ + q0 + rq) * C_ + h * 64 + df * 16 + quad * 4] = yv;
                }
            }
        }
    }
}

#define MB(x) ((size_t)(x) << 20)

extern "C" void kernel_launch(void* const* d_in, const int* in_sizes, int n_in,
                              void* d_out, int out_size, void* d_ws, size_t ws_size,
                              hipStream_t stream) {
    const float* x      = (const float*)d_in[0];
    const float* ln1_w  = (const float*)d_in[1];
    const float* ln1_b  = (const float*)d_in[2];
    const float* w_attn = (const float*)d_in[3];
    const float* b_attn = (const float*)d_in[4];
    const float* w_proj = (const float*)d_in[5];
    const float* b_proj = (const float*)d_in[6];
    const float* ln2_w  = (const float*)d_in[7];
    const float* ln2_b  = (const float*)d_in[8];
    const float* w_fc   = (const float*)d_in[9];
    const float* b_fc   = (const float*)d_in[10];
    const float* w_fc2  = (const float*)d_in[11];
    const float* b_fc2  = (const float*)d_in[12];
    float* out = (float*)d_out;

    char* ws = (char*)d_ws;
    unsigned short* wT1  = (unsigned short*)(ws + MB(0));   // [3072,1024] 6MB
    unsigned short* wT2  = (unsigned short*)(ws + MB(6));   // [1024,1024] 2MB
    unsigned short* wT3  = (unsigned short*)(ws + MB(8));   // [4096,1024] 8MB
    unsigned short* wT4  = (unsigned short*)(ws + MB(16));  // [1024,4096] 8MB
    unsigned short* h_bf = (unsigned short*)(ws + MB(24));  // [4096,1024] 8MB (h, then h2)
    unsigned short* qkv  = (unsigned short*)(ws + MB(32));  // [4096,3072] 24MB (V third unused)
    unsigned short* Vt   = (unsigned short*)(ws + MB(56));  // [32*64,2048] 8MB (written by qkv GEMM)
    unsigned short* y_bf = (unsigned short*)(ws + MB(64));  // [4096,1024] 8MB
    float*          x1   = (float*)(ws + MB(72));           // [4096,1024] 16MB fp32
    unsigned short* f_bf = (unsigned short*)(ws + MB(88));  // [4096,4096] 32MB
    float*          part = (float*)(ws + MB(32));           // 2x[4096,1024] fp32 = 32MB
                                                            // (reuses dead qkv+Vt region)
    dim3 b256(256), b512(512);

    // weights transpose+cast + LN1 in one launch (independent inputs)
    prep_kernel<<<12288 + M_, b256, 0, stream>>>(w_attn, wT1, w_proj, wT2,
                                                 w_fc, wT3, w_fc2, wT4,
                                                 x, ln1_w, ln1_b, h_bf);
    // qkv = h @ w_attn + b_attn; Q cols pre-scaled by 0.125*log2(e);
    // V third written transposed straight into Vt (fused transpose_v)
    bgemm<0,1,128,1,1,1,0><<<dim3(3*C_/128, M_/128), b256, 0, stream>>>(
        h_bf, wT1, b_attn, nullptr, qkv, Vt, M_, 3*C_, C_);
    attn_kernel<<<512, b256, 0, stream>>>(qkv, Vt, y_bf);
    bgemm<0,0,64,0,1,0,0><<<dim3(C_/64, M_/128), b256, 0, stream>>>(
        y_bf, wT2, b_proj, x, x1, nullptr, M_, C_, C_);
    ln_bf16<<<M_, b256, 0, stream>>>(x1, ln2_w, ln2_b, h_bf);
    // fc: deep-pipelined 256x256 tile, 256 blocks (1/CU), XCD swizzle (16 n-tiles % 8 == 0)
    bgemm2<1,1,256,0,1,0,1><<<dim3(4*C_/256, M_/256), b512, 0, stream>>>(
        h_bf, wT3, b_fc, nullptr, f_bf, nullptr, M_, 4*C_, C_);
    // fc2: deep-pipelined 128x256 tile, K-split=2, XS=2 flat remap: each XCD
    // owns one (n-tile, K-half) -> B strip 1MB L2-resident, A streamed once
    bgemm2<0,0,128,0,2,0,2><<<dim3(C_/256, M_/128, 2), b512, 0, stream>>>(
        f_bf, wT4, nullptr, nullptr, part, nullptr, M_, C_, 4*C_);
    combine_out<<<(M_*C_)/(4*256), b256, 0, stream>>>(part, b_fc2, x1, out);
}